// Round 21
// baseline (151.318 us; speedup 1.0000x reference)
//
#include <hip/hip_runtime.h>
#include <hip/hip_bf16.h>
#include <math.h>

// ---- problem constants ----
#define B_ROWS 512
#define D_K    512
#define C_CLS  100000
#define C_PAD  100032

#define COS_M 0.8775825618903728f
#define SIN_M 0.479425538604203f
#define TH_C  (-0.8775825618903728f)    // cos(pi - m)
#define MM_C  0.2397127693021015f       // sin(pi - m) * m

#define LOG2E_S 92.33248261689366f      // 64 * log2(e)
#define M0      92.4f
#define LN2F    0.6931471805599453f

#define BN 64
#define NCHUNK 1563
#define NSTRIP 256                      // one block per strip

typedef __attribute__((ext_vector_type(4))) float f32x4;
typedef __attribute__((ext_vector_type(4))) int   i32x4;
typedef __attribute__((ext_vector_type(2))) long long i64x2;

__device__ inline float fexp2(float x) {
#if __has_builtin(__builtin_amdgcn_exp2f)
    return __builtin_amdgcn_exp2f(x);
#else
    return exp2f(x);
#endif
}
__device__ inline void gload16(const void* g, void* lds) {
    __builtin_amdgcn_global_load_lds(
        (const __attribute__((address_space(1))) unsigned int*)g,
        (__attribute__((address_space(3))) unsigned int*)lds, 16, 0, 0);
}
#define VMCNT0() asm volatile("s_waitcnt vmcnt(0)" ::: "memory")
#define RAWBAR() __builtin_amdgcn_s_barrier()

// ---------------- kernel 0: x rows -> normalized fp8, kk-interleaved ----------------
__global__ __launch_bounds__(256) void rownorm8p_kernel(const float* __restrict__ in,
                                                        uint2* __restrict__ out,
                                                        float* __restrict__ rnout,
                                                        int nvalid) {
    const int wid = threadIdx.x >> 6;
    const int lane = threadIdx.x & 63;
    const int r = blockIdx.x * 4 + wid;
    const int newg = ((lane >> 3) << 3) + ((lane & 3) << 1) + ((lane >> 2) & 1);
    if (r >= nvalid) {
        out[(size_t)r * 64 + newg] = make_uint2(0u, 0u);
        return;
    }
    const float* row = in + (size_t)r * D_K + lane * 8;
    float4 a = *(const float4*)row;
    float4 b = *(const float4*)(row + 4);
    float ss = a.x * a.x + a.y * a.y + a.z * a.z + a.w * a.w
             + b.x * b.x + b.y * b.y + b.z * b.z + b.w * b.w;
    ss += __shfl_xor(ss, 1);  ss += __shfl_xor(ss, 2);  ss += __shfl_xor(ss, 4);
    ss += __shfl_xor(ss, 8);  ss += __shfl_xor(ss, 16); ss += __shfl_xor(ss, 32);
    const float rn = 1.0f / sqrtf(ss);
    int u0 = __builtin_amdgcn_cvt_pk_fp8_f32(a.x * rn, a.y * rn, 0, false);
    u0     = __builtin_amdgcn_cvt_pk_fp8_f32(a.z * rn, a.w * rn, u0, true);
    int u1 = __builtin_amdgcn_cvt_pk_fp8_f32(b.x * rn, b.y * rn, 0, false);
    u1     = __builtin_amdgcn_cvt_pk_fp8_f32(b.z * rn, b.w * rn, u1, true);
    out[(size_t)r * 64 + newg] = make_uint2((unsigned)u0, (unsigned)u1);
    if (rnout != nullptr && lane == 0) rnout[r] = rn;
}

// ---------------- kernel 1: strip-owner fused kernel ----------------
// One 512-thread block (8 waves) per strip. Per iteration ci:
//   1. stage chunk ci+1 (global_load_lds from wn8, written 2 iters ago, drained)
//   2. 8 ksteps: issue W fp32 loads for chunk ci+2 (kstep k), MFMA kstep k of ci,
//      convert kstep k-1 (raw fp8, ss folded) -> wn8 global (flows via L2)
//   3. rn finalize for ci+2 -> rnorm_g
//   4. fixed-M0 epilogue for ci (rn applied post-dot)
//   5. vmcnt(0) + s_barrier  (drains wnorm stores; stage gloads landed under compute)
// W fp32 read ONCE device-wide, overlapped with MFMA. No cross-block deps.
__global__ __launch_bounds__(512, 2) void strip_fused_kernel(
        const unsigned char* __restrict__ xnb8p,  // [512][512] fp8 norm, interleaved
        const float* __restrict__ w,              // [100000][512] fp32 raw
        unsigned char* __restrict__ wn8,          // [C_PAD][512] fp8 raw-quant, interleaved
        float* __restrict__ rnorm_g,              // [C_PAD]
        float* __restrict__ partials) {           // [NSTRIP][512]
    const int t    = threadIdx.x;
    const int lane = t & 63;
    const int wid  = t >> 6;                      // 0..7
    const int cl   = lane & 15;
    const int hi   = lane >> 4;
    const int swz  = (cl >> 1) & 3;

    const int s   = blockIdx.x;
    const int ch0 = (s * NCHUNK) >> 8;
    const int ch1 = ((s + 1) * NCHUNK) >> 8;
    const int nch = ch1 - ch0;
    const int cbase = ch0 * BN;

    __shared__ char smem[2 * 32768];              // 2-chunk B ring (64 KB)

    // ---- staging identity (r15 pattern, scaled): wave wid stages kslice wid ----
    const int srowS = lane >> 2;                  // row base within 16-row group
    const int gS    = lane & 3;

#define STAGE_CHUNK(ci_, buf_)                                                   \
    {                                                                            \
        _Pragma("unroll")                                                        \
        for (int _i = 0; _i < 4; ++_i) {                                         \
            const int _row = _i * 16 + srowS;                                    \
            const int _sg  = gS ^ ((_row >> 1) & 3);                             \
            gload16(wn8 + (size_t)(cbase + (ci_) * 64 + _row) * 512 +            \
                        wid * 64 + _sg * 16,                                     \
                    smem + (buf_) * 32768 + wid * 4096 + _i * 1024 + lane * 16); \
        }                                                                        \
    }

    // ---- wnorm identity: thread covers row rW = t>>3, kslice seg = t&7 ----
    const int rW  = t >> 3;
    const int seg = t & 7;

    f32x4 pA0, pA1, pB0, pB1;
    float ssv = 0.f;
    int   cw64 = 0;                               // row base of chunk being wnormed

#define ISSUEW(k, S)                                                             \
    {                                                                            \
        int _c = cw64 + rW;                                                      \
        _c = _c < C_CLS ? _c : C_CLS - 1;                                        \
        const float* _p = w + (size_t)_c * 512 + seg * 64 + (k) * 8;             \
        p##S##0 = *(const f32x4*)_p;                                             \
        p##S##1 = *(const f32x4*)(_p + 4);                                       \
    }
#define CONVW(k, S)                                                              \
    {                                                                            \
        f32x4 _a = p##S##0, _b = p##S##1;                                        \
        ssv += _a[0]*_a[0] + _a[1]*_a[1] + _a[2]*_a[2] + _a[3]*_a[3]             \
             + _b[0]*_b[0] + _b[1]*_b[1] + _b[2]*_b[2] + _b[3]*_b[3];            \
        int _u0 = __builtin_amdgcn_cvt_pk_fp8_f32(_a[0], _a[1], 0, false);       \
        _u0     = __builtin_amdgcn_cvt_pk_fp8_f32(_a[2], _a[3], _u0, true);      \
        int _u1 = __builtin_amdgcn_cvt_pk_fp8_f32(_b[0], _b[1], 0, false);       \
        _u1     = __builtin_amdgcn_cvt_pk_fp8_f32(_b[2], _b[3], _u1, true);      \
        *(uint2*)(wn8 + (size_t)(cw64 + rW) * 512 + seg * 64 +                   \
                  ((k) & 3) * 16 + ((k) >> 2) * 8) =                             \
            make_uint2((unsigned)_u0, (unsigned)_u1);                            \
    }
#define RNFIN()                                                                  \
    {                                                                            \
        float _s = ssv;                                                          \
        _s += __shfl_xor(_s, 1); _s += __shfl_xor(_s, 2); _s += __shfl_xor(_s, 4);\
        if (seg == 0)                                                            \
            rnorm_g[cw64 + rW] =                                                 \
                (cw64 + rW < C_CLS) ? (1.0f / sqrtf(_s)) : 0.0f;                 \
        ssv = 0.f;                                                               \
    }

    // ---- A: 64 rows/wave, full K, volatile-asm loads (un-rematerializable) ----
    i32x4 a8v[4][8];
#pragma unroll
    for (int m = 0; m < 4; ++m) {
        const unsigned char* ap =
            xnb8p + (size_t)(wid * 64 + m * 16 + cl) * 512 + hi * 16;
#pragma unroll
        for (int k = 0; k < 8; ++k) {
            unsigned long long addr = (unsigned long long)(ap + k * 64);
            asm volatile("global_load_dwordx4 %0, %1, off"
                         : "=v"(a8v[m][k]) : "v"(addr));
        }
    }
    VMCNT0();

    // ---- prologue: wnorm chunks 0,1 (2-deep pipelined); stage chunk 0 ----
#pragma unroll
    for (int pc = 0; pc < 2; ++pc) {
        cw64 = cbase + pc * 64;
        ISSUEW(0, A) ISSUEW(1, B)
        CONVW(0, A) ISSUEW(2, A)
        CONVW(1, B) ISSUEW(3, B)
        CONVW(2, A) ISSUEW(4, A)
        CONVW(3, B) ISSUEW(5, B)
        CONVW(4, A) ISSUEW(6, A)
        CONVW(5, B) ISSUEW(7, B)
        CONVW(6, A)
        CONVW(7, B)
        RNFIN()
    }
    VMCNT0();
    RAWBAR();
    STAGE_CHUNK(0, 0)
    VMCNT0();
    RAWBAR();

    float sums[16];
#pragma unroll
    for (int i = 0; i < 16; ++i) sums[i] = 0.f;

#define CK(bufbyte, k)                                                           \
    {                                                                            \
        const char* sB = smem + (bufbyte) + (k) * 4096;                          \
        i64x2 bfr[4];                                                            \
        _Pragma("unroll")                                                        \
        for (int n = 0; n < 4; ++n)                                              \
            bfr[n] = *(const i64x2*)(sB + (n * 16 + cl) * 64 +                   \
                                     ((hi ^ swz) << 4));                         \
        _Pragma("unroll")                                                        \
        for (int m = 0; m < 4; ++m) {                                            \
            const i64x2 av = __builtin_bit_cast(i64x2, a8v[m][k]);               \
            _Pragma("unroll")                                                    \
            for (int n = 0; n < 4; ++n)                                          \
                acc[m][n] = __builtin_amdgcn_mfma_f32_16x16x32_fp8_fp8(          \
                    av[0], bfr[n][0], acc[m][n], 0, 0, 0);                       \
            _Pragma("unroll")                                                    \
            for (int n = 0; n < 4; ++n)                                          \
                acc[m][n] = __builtin_amdgcn_mfma_f32_16x16x32_fp8_fp8(          \
                    av[1], bfr[n][1], acc[m][n], 0, 0, 0);                       \
        }                                                                        \
    }

    for (int ci = 0; ci < nch; ++ci) {
        const bool stg = (ci + 1) < nch;
        const bool wna = (ci + 2) < nch;
        cw64 = cbase + (ci + 2) * 64;
        const int bb = (ci & 1) * 32768;

        if (stg) STAGE_CHUNK(ci + 1, (ci + 1) & 1)

        // rn for THIS chunk (written 2 iters ago; drained + barriered)
        float rlv[4];
#pragma unroll
        for (int n = 0; n < 4; ++n)
            rlv[n] = rnorm_g[cbase + ci * 64 + n * 16 + cl];

        f32x4 acc[4][4];
#pragma unroll
        for (int m = 0; m < 4; ++m)
#pragma unroll
            for (int n = 0; n < 4; ++n) acc[m][n] = (f32x4){0.f, 0.f, 0.f, 0.f};

        // 8 ksteps: issue W(ci+2,k) -> MFMA(ci,k) -> convert W(ci+2,k-1)
        if (wna) ISSUEW(0, A)
        CK(bb, 0)
        if (wna) ISSUEW(1, B)
        CK(bb, 1)
        if (wna) CONVW(0, A)
        if (wna) ISSUEW(2, A)
        CK(bb, 2)
        if (wna) CONVW(1, B)
        if (wna) ISSUEW(3, B)
        CK(bb, 3)
        if (wna) CONVW(2, A)
        if (wna) ISSUEW(4, A)
        CK(bb, 4)
        if (wna) CONVW(3, B)
        if (wna) ISSUEW(5, B)
        CK(bb, 5)
        if (wna) CONVW(4, A)
        if (wna) ISSUEW(6, A)
        CK(bb, 6)
        if (wna) CONVW(5, B)
        if (wna) ISSUEW(7, B)
        CK(bb, 7)
        if (wna) {
            CONVW(6, A)
            CONVW(7, B)
            RNFIN()
        }

        // fixed-M0 epilogue with post-dot row norm (pad rows: rn=0 -> 2^-92.4)
        {
            float rl[4];
#pragma unroll
            for (int n = 0; n < 4; ++n) rl[n] = rlv[n] * LOG2E_S;
#pragma unroll
            for (int m = 0; m < 4; ++m)
#pragma unroll
                for (int jj = 0; jj < 4; ++jj)
#pragma unroll
                    for (int n = 0; n < 4; ++n)
                        sums[m * 4 + jj] += fexp2(fmaf(acc[m][n][jj], rl[n], -M0));
        }

        VMCNT0();   // drains wnorm stores (ci+2) + stage gloads (ci+1)
        RAWBAR();
    }
#undef STAGE_CHUNK
#undef ISSUEW
#undef CONVW
#undef RNFIN
#undef CK

    // ---- strip epilogue ----
#pragma unroll
    for (int m = 0; m < 4; ++m)
#pragma unroll
        for (int jj = 0; jj < 4; ++jj) {
            float v = sums[m * 4 + jj];
            v += __shfl_xor(v, 1);
            v += __shfl_xor(v, 2);
            v += __shfl_xor(v, 4);
            v += __shfl_xor(v, 8);
            if (cl == 0) {
                const int r = wid * 64 + m * 16 + hi * 4 + jj;
                partials[s * B_ROWS + r] = v;
            }
        }
}

// ---------------- kernel 2: target-class cosine (fp32 exact) ----------------
__global__ __launch_bounds__(256) void tdot_kernel(const float* __restrict__ x,
                                                   const float* __restrict__ w,
                                                   const int* __restrict__ tgt,
                                                   const float* __restrict__ xrn,
                                                   float* __restrict__ tdot) {
    const int wid = threadIdx.x >> 6;
    const int lane = threadIdx.x & 63;
    const int b = blockIdx.x * 4 + wid;
    const int tg = tgt[b];
    const float* xr = x + (size_t)b * D_K + lane * 8;
    const float* wr = w + (size_t)tg * D_K + lane * 8;
    float4 xa = *(const float4*)xr;
    float4 xb = *(const float4*)(xr + 4);
    float4 wa = *(const float4*)wr;
    float4 wb = *(const float4*)(wr + 4);
    float xw = xa.x * wa.x + xa.y * wa.y + xa.z * wa.z + xa.w * wa.w
             + xb.x * wb.x + xb.y * wb.y + xb.z * wb.z + xb.w * wb.w;
    float ww = wa.x * wa.x + wa.y * wa.y + wa.z * wa.z + wa.w * wa.w
             + wb.x * wb.x + wb.y * wb.y + wb.z * wb.z + wb.w * wb.w;
#pragma unroll
    for (int m = 1; m < 64; m <<= 1) {
        xw += __shfl_xor(xw, m);
        ww += __shfl_xor(ww, m);
    }
    if (lane == 0) tdot[b] = xw * xrn[b] / sqrtf(ww);
}

// ---------------- kernel 3: per-row loss (margin fixup) + mean ----------------
__global__ __launch_bounds__(512) void final_kernel(const float* __restrict__ partials,
                                                    const float* __restrict__ tdot,
                                                    float* __restrict__ out) {
    const int b = threadIdx.x;
    float s2 = 0.f;
    for (int s = 0; s < NSTRIP; ++s) s2 += partials[s * B_ROWS + b];
    const float cst = tdot[b];
    float c2 = 1.0f - cst * cst;
    c2 = fminf(fmaxf(c2, 0.0f), 1.0f);
    const float sine = sqrtf(c2);
    float phi = cst * COS_M - sine * SIN_M;
    phi = (cst > TH_C) ? phi : (cst - MM_C);
    const float Lt = cst * LOG2E_S;
    const float Lp = phi * LOG2E_S;
    s2 = s2 - fexp2(Lt - M0) + fexp2(Lp - M0);
    float loss = LN2F * (M0 + log2f(s2) - Lp);
    loss += __shfl_xor(loss, 1);  loss += __shfl_xor(loss, 2);
    loss += __shfl_xor(loss, 4);  loss += __shfl_xor(loss, 8);
    loss += __shfl_xor(loss, 16); loss += __shfl_xor(loss, 32);
    __shared__ float sW[8];
    if ((b & 63) == 0) sW[b >> 6] = loss;
    __syncthreads();
    if (b == 0) {
        float tot = 0.f;
#pragma unroll
        for (int wv = 0; wv < 8; ++wv) tot += sW[wv];
        out[0] = tot * (1.0f / (float)B_ROWS);
    }
}

extern "C" void kernel_launch(void* const* d_in, const int* in_sizes, int n_in,
                              void* d_out, int out_size, void* d_ws, size_t ws_size,
                              hipStream_t stream) {
    const float* x = (const float*)d_in[0];
    const float* w = (const float*)d_in[1];
    const int* tgt = (const int*)d_in[2];
    float* out = (float*)d_out;

    char* ws = (char*)d_ws;
    size_t off = 0;
    unsigned char* xnb8 = (unsigned char*)(ws + off);
    off += (size_t)B_ROWS * D_K;                       // 256 KB
    off = (off + 255) & ~(size_t)255;
    unsigned char* wn8 = (unsigned char*)(ws + off);
    off += (size_t)C_PAD * D_K;                        // 51.2 MB
    off = (off + 255) & ~(size_t)255;
    float* rnorm_g = (float*)(ws + off);
    off += (size_t)C_PAD * 4;                          // 400 KB
    off = (off + 255) & ~(size_t)255;
    float* xrn = (float*)(ws + off);
    off += B_ROWS * 4;
    off = (off + 255) & ~(size_t)255;
    float* partials = (float*)(ws + off);
    off += (size_t)NSTRIP * B_ROWS * 4;                // 512 KB
    off = (off + 255) & ~(size_t)255;
    float* tdot = (float*)(ws + off);
    off += B_ROWS * 4;

    rownorm8p_kernel<<<B_ROWS / 4, 256, 0, stream>>>(x, (uint2*)xnb8, xrn, B_ROWS);
    tdot_kernel<<<B_ROWS / 4, 256, 0, stream>>>(x, w, tgt, xrn, tdot);
    strip_fused_kernel<<<NSTRIP, 512, 0, stream>>>(xnb8, w, wn8, rnorm_g, partials);
    final_kernel<<<1, 512, 0, stream>>>(partials, tdot, out);
}

// Round 22
// 131.762 us; speedup vs baseline: 1.1484x; 1.1484x over previous
//
#include <hip/hip_runtime.h>
#include <hip/hip_bf16.h>
#include <math.h>

// ---- problem constants ----
#define B_ROWS 512
#define D_K    512
#define C_CLS  100000
#define C_PAD  100032

#define COS_M 0.8775825618903728f
#define SIN_M 0.479425538604203f
#define TH_C  (-0.8775825618903728f)    // cos(pi - m)
#define MM_C  0.2397127693021015f       // sin(pi - m) * m

#define LOG2E_S 92.33248261689366f      // 64 * log2(e)
#define M0      92.4f
#define LN2F    0.6931471805599453f

#define BN 64
#define NCHUNK 1563
#define NSTRIP 256

typedef __attribute__((ext_vector_type(4))) float f32x4;
typedef __attribute__((ext_vector_type(4))) int   i32x4;
typedef __attribute__((ext_vector_type(2))) long long i64x2;

__device__ inline float fexp2(float x) {
#if __has_builtin(__builtin_amdgcn_exp2f)
    return __builtin_amdgcn_exp2f(x);
#else
    return exp2f(x);
#endif
}
#define VMCNT0() asm volatile("s_waitcnt vmcnt(0)" ::: "memory")
#define VMCNT4() asm volatile("s_waitcnt vmcnt(4)" ::: "memory")
#define SCHED0() __builtin_amdgcn_sched_barrier(0)

// ---------------- kernel 0: row-normalize -> fp8 e4m3, kk-INTERLEAVED layout ------
// Per-row byte permutation: pos = ks*64 + hi*16 + kk*8 + inner for original
// k-byte = ks*64 + kk*32 + hi*8 + inner.  A 16B read at row*512 + ks*64 + hi*16
// yields the (kk0,kk1) MFMA fragment pair for lane-group hi, contiguous.
__global__ __launch_bounds__(256) void rownorm8p_kernel(const float* __restrict__ in,
                                                        uint2* __restrict__ out,
                                                        float* __restrict__ rnout,
                                                        int nvalid) {
    const int wid = threadIdx.x >> 6;
    const int lane = threadIdx.x & 63;
    const int r = blockIdx.x * 4 + wid;
    const int newg = ((lane >> 3) << 3) + ((lane & 3) << 1) + ((lane >> 2) & 1);
    if (r >= nvalid) {
        out[(size_t)r * 64 + newg] = make_uint2(0u, 0u);
        return;
    }
    const float* row = in + (size_t)r * D_K + lane * 8;
    float4 a = *(const float4*)row;
    float4 b = *(const float4*)(row + 4);
    float ss = a.x * a.x + a.y * a.y + a.z * a.z + a.w * a.w
             + b.x * b.x + b.y * b.y + b.z * b.z + b.w * b.w;
    ss += __shfl_xor(ss, 1);  ss += __shfl_xor(ss, 2);  ss += __shfl_xor(ss, 4);
    ss += __shfl_xor(ss, 8);  ss += __shfl_xor(ss, 16); ss += __shfl_xor(ss, 32);
    const float rn = 1.0f / sqrtf(ss);
    int u0 = __builtin_amdgcn_cvt_pk_fp8_f32(a.x * rn, a.y * rn, 0, false);
    u0     = __builtin_amdgcn_cvt_pk_fp8_f32(a.z * rn, a.w * rn, u0, true);
    int u1 = __builtin_amdgcn_cvt_pk_fp8_f32(b.x * rn, b.y * rn, 0, false);
    u1     = __builtin_amdgcn_cvt_pk_fp8_f32(b.z * rn, b.w * rn, u1, true);
    out[(size_t)r * 64 + newg] = make_uint2((unsigned)u0, (unsigned)u1);
    if (rnout != nullptr && lane == 0) rnout[r] = rn;
}

// ---------------- kernel 1: BARRIER-FREE fp8 strip GEMM (L2-direct B) ------------
// No LDS, no barriers, no __syncthreads. 4 waves/block, wave owns 64 rows.
// A fp8 pinned via volatile-asm dwordx4 loads (128 VGPR, un-rematerializable).
// B: per-lane dwordx4 = both kk-fragments, depth-2 volatile ring bv[2][4],
// counted vmcnt(4) + sched_barrier.  The block's 4 waves read identical B
// addresses -> L1 serves 3/4; unique traffic ~100 MB from L2/L3.
__global__ __launch_bounds__(256, 2) void gemm_nosync_kernel(
        const unsigned char* __restrict__ xnb8p,  // [512][512] fp8 norm, interleaved
        const unsigned char* __restrict__ wn8p,   // [C_PAD][512] fp8 norm, interleaved
        float* __restrict__ partials) {           // [NSTRIP][512]
    const int t    = threadIdx.x;
    const int lane = t & 63;
    const int wid  = t >> 6;
    const int cl   = lane & 15;
    const int hi   = lane >> 4;

    // XCD-pair mapping: rb-twins of a strip share an XCD -> wn8p L2-shared.
    const int j   = blockIdx.x;
    const int s   = (j & 7) * 32 + ((j >> 3) >> 1);   // col-strip 0..255
    const int rb  = (j >> 3) & 1;                     // rowblock
    const int ch0 = (s * NCHUNK) >> 8;
    const int ch1 = ((s + 1) * NCHUNK) >> 8;
    const int nch = ch1 - ch0;
    const int cbase = ch0 * BN;
    const int G   = nch * 8;                          // total ksteps in strip

    // ---- A: 64 rows/wave, full K, volatile-asm loads (pinned, 128 VGPR) ----
    i32x4 a8v[4][8];
#pragma unroll
    for (int m = 0; m < 4; ++m) {
        const unsigned char* ap =
            xnb8p + (size_t)(rb * 256 + wid * 64 + m * 16 + cl) * 512 + hi * 16;
#pragma unroll
        for (int k = 0; k < 8; ++k) {
            unsigned long long addr = (unsigned long long)(ap + k * 64);
            asm volatile("global_load_dwordx4 %0, %1, off"
                         : "=v"(a8v[m][k]) : "v"(addr));
        }
    }
    VMCNT0();

    // ---- B: per-lane base for each n-tile; depth-2 volatile ring ----
    const unsigned char* pB[4];
#pragma unroll
    for (int n = 0; n < 4; ++n)
        pB[n] = wn8p + (size_t)(cbase + n * 16 + cl) * 512 + hi * 16;

    i32x4 bv[2][4];
#define ISSUEB(g, slot)                                                         \
    {                                                                           \
        const int _g = (g) < G ? (g) : G - 1;                                   \
        const size_t _off = (size_t)(_g >> 3) * 32768 + (size_t)(_g & 7) * 64;  \
        _Pragma("unroll")                                                       \
        for (int n = 0; n < 4; ++n) {                                           \
            unsigned long long _a = (unsigned long long)(pB[n] + _off);         \
            asm volatile("global_load_dwordx4 %0, %1, off"                      \
                         : "=v"(bv[slot][n]) : "v"(_a));                        \
        }                                                                       \
    }

    // prologue: ksteps 0,1 in flight (8 outstanding)
    ISSUEB(0, 0)
    ISSUEB(1, 1)

    float sums[16];
#pragma unroll
    for (int i = 0; i < 16; ++i) sums[i] = 0.f;

    // STEP(k): wait oldest 4 (kstep k landed; k+1 in flight), MFMA, issue k+2
#define STEP(k)                                                                 \
    {                                                                           \
        VMCNT4();                                                               \
        SCHED0();                                                               \
        _Pragma("unroll")                                                       \
        for (int m = 0; m < 4; ++m) {                                           \
            const i64x2 av = __builtin_bit_cast(i64x2, a8v[m][k]);              \
            _Pragma("unroll")                                                   \
            for (int n = 0; n < 4; ++n) {                                       \
                const i64x2 bb = __builtin_bit_cast(i64x2, bv[(k) & 1][n]);     \
                acc[m][n] = __builtin_amdgcn_mfma_f32_16x16x32_fp8_fp8(         \
                    av[0], bb[0], acc[m][n], 0, 0, 0);                          \
                acc[m][n] = __builtin_amdgcn_mfma_f32_16x16x32_fp8_fp8(         \
                    av[1], bb[1], acc[m][n], 0, 0, 0);                          \
            }                                                                   \
        }                                                                       \
        ISSUEB(ci * 8 + (k) + 2, (k) & 1)                                       \
    }

    for (int ci = 0; ci < nch; ++ci) {
        f32x4 acc[4][4];
#pragma unroll
        for (int m = 0; m < 4; ++m)
#pragma unroll
            for (int n = 0; n < 4; ++n) acc[m][n] = (f32x4){0.f, 0.f, 0.f, 0.f};

        STEP(0) STEP(1) STEP(2) STEP(3) STEP(4) STEP(5) STEP(6) STEP(7)

        // fixed-M0 accumulation (rows pre-normalized; pad classes -> 2^-92.4 ~ 0)
#pragma unroll
        for (int m = 0; m < 4; ++m)
#pragma unroll
            for (int jj = 0; jj < 4; ++jj)
#pragma unroll
                for (int n = 0; n < 4; ++n)
                    sums[m * 4 + jj] += fexp2(fmaf(acc[m][n][jj], LOG2E_S, -M0));
    }
#undef ISSUEB
#undef STEP
    VMCNT0();   // drain trailing dummy loads before epilogue/endpgm

    // ---- strip epilogue: reduce each tracked row across its 16 col-lanes ----
#pragma unroll
    for (int m = 0; m < 4; ++m)
#pragma unroll
        for (int jj = 0; jj < 4; ++jj) {
            float v = sums[m * 4 + jj];
            v += __shfl_xor(v, 1);
            v += __shfl_xor(v, 2);
            v += __shfl_xor(v, 4);
            v += __shfl_xor(v, 8);
            if (cl == 0) {
                const int r = rb * 256 + wid * 64 + m * 16 + hi * 4 + jj;
                partials[s * B_ROWS + r] = v;
            }
        }
}

// ---------------- kernel 2: target-class cosine (fp32 exact) ----------------
__global__ __launch_bounds__(256) void tdot_kernel(const float* __restrict__ x,
                                                   const float* __restrict__ w,
                                                   const int* __restrict__ tgt,
                                                   const float* __restrict__ xrn,
                                                   float* __restrict__ tdot) {
    const int wid = threadIdx.x >> 6;
    const int lane = threadIdx.x & 63;
    const int b = blockIdx.x * 4 + wid;
    const int tg = tgt[b];
    const float* xr = x + (size_t)b * D_K + lane * 8;
    const float* wr = w + (size_t)tg * D_K + lane * 8;
    float4 xa = *(const float4*)xr;
    float4 xb = *(const float4*)(xr + 4);
    float4 wa = *(const float4*)wr;
    float4 wb = *(const float4*)(wr + 4);
    float xw = xa.x * wa.x + xa.y * wa.y + xa.z * wa.z + xa.w * wa.w
             + xb.x * wb.x + xb.y * wb.y + xb.z * wb.z + xb.w * wb.w;
    float ww = wa.x * wa.x + wa.y * wa.y + wa.z * wa.z + wa.w * wa.w
             + wb.x * wb.x + wb.y * wb.y + wb.z * wb.z + wb.w * wb.w;
#pragma unroll
    for (int m = 1; m < 64; m <<= 1) {
        xw += __shfl_xor(xw, m);
        ww += __shfl_xor(ww, m);
    }
    if (lane == 0) tdot[b] = xw * xrn[b] / sqrtf(ww);
}

// ---------------- kernel 3: per-row loss (margin fixup) + mean ----------------
__global__ __launch_bounds__(512) void final_kernel(const float* __restrict__ partials,
                                                    const float* __restrict__ tdot,
                                                    float* __restrict__ out) {
    const int b = threadIdx.x;   // 512 threads = 8 waves
    float s2 = 0.f;
    for (int s = 0; s < NSTRIP; ++s) s2 += partials[s * B_ROWS + b];
    const float cst = tdot[b];
    float c2 = 1.0f - cst * cst;
    c2 = fminf(fmaxf(c2, 0.0f), 1.0f);
    const float sine = sqrtf(c2);
    float phi = cst * COS_M - sine * SIN_M;
    phi = (cst > TH_C) ? phi : (cst - MM_C);
    const float Lt = cst * LOG2E_S;
    const float Lp = phi * LOG2E_S;
    s2 = s2 - fexp2(Lt - M0) + fexp2(Lp - M0);
    float loss = LN2F * (M0 + log2f(s2) - Lp);
    loss += __shfl_xor(loss, 1);  loss += __shfl_xor(loss, 2);
    loss += __shfl_xor(loss, 4);  loss += __shfl_xor(loss, 8);
    loss += __shfl_xor(loss, 16); loss += __shfl_xor(loss, 32);
    __shared__ float sW[8];
    if ((b & 63) == 0) sW[b >> 6] = loss;
    __syncthreads();
    if (b == 0) {
        float tot = 0.f;
#pragma unroll
        for (int wv = 0; wv < 8; ++wv) tot += sW[wv];
        out[0] = tot * (1.0f / (float)B_ROWS);
    }
}

extern "C" void kernel_launch(void* const* d_in, const int* in_sizes, int n_in,
                              void* d_out, int out_size, void* d_ws, size_t ws_size,
                              hipStream_t stream) {
    const float* x = (const float*)d_in[0];
    const float* w = (const float*)d_in[1];
    const int* tgt = (const int*)d_in[2];
    float* out = (float*)d_out;

    char* ws = (char*)d_ws;
    size_t off = 0;
    unsigned char* xnb8 = (unsigned char*)(ws + off);
    off += (size_t)B_ROWS * D_K;                       // 256 KB
    off = (off + 255) & ~(size_t)255;
    unsigned char* wn8 = (unsigned char*)(ws + off);
    off += (size_t)C_PAD * D_K;                        // 51.2 MB
    off = (off + 255) & ~(size_t)255;
    float* xrn = (float*)(ws + off);
    off += B_ROWS * 4;
    off = (off + 255) & ~(size_t)255;
    float* partials = (float*)(ws + off);
    off += (size_t)NSTRIP * B_ROWS * 4;                // 512 KB
    off = (off + 255) & ~(size_t)255;
    float* tdot = (float*)(ws + off);
    off += B_ROWS * 4;

    rownorm8p_kernel<<<B_ROWS / 4, 256, 0, stream>>>(x, (uint2*)xnb8, xrn, B_ROWS);
    rownorm8p_kernel<<<C_PAD / 4, 256, 0, stream>>>(w, (uint2*)wn8, nullptr, C_CLS);
    tdot_kernel<<<B_ROWS / 4, 256, 0, stream>>>(x, w, tgt, xrn, tdot);
    gemm_nosync_kernel<<<NSTRIP * 2, 256, 0, stream>>>(xnb8, wn8, partials);
    final_kernel<<<1, 512, 0, stream>>>(partials, tdot, out);
}

// Round 23
// 95.222 us; speedup vs baseline: 1.5891x; 1.3837x over previous
//
#include <hip/hip_runtime.h>
#include <hip/hip_bf16.h>
#include <math.h>

// ---- problem constants ----
#define B_ROWS 512
#define D_K    512
#define C_CLS  100000
#define C_PAD  100032                   // NCHUNK*64 (pad rows = fp8 zeros)

#define COS_M 0.8775825618903728f
#define SIN_M 0.479425538604203f
#define TH_C  (-0.8775825618903728f)    // cos(pi - m)
#define MM_C  0.2397127693021015f       // sin(pi - m) * m

#define LOG2E_S 92.33248261689366f      // 64 * log2(e)
#define M0      92.4f                   // fixed softmax bound: |cos|<=1 -> |L|<=92.33
#define LN2F    0.6931471805599453f

#define BN 64                           // classes per chunk
#define NCHUNK 1563                     // ceil(100000/64)
#define NSTRIP 256                      // col-strips

typedef __attribute__((ext_vector_type(4))) float f32x4;
typedef __attribute__((ext_vector_type(2))) long long i64x2;
typedef long long i64;

__device__ inline float fexp2(float x) {
#if __has_builtin(__builtin_amdgcn_exp2f)
    return __builtin_amdgcn_exp2f(x);
#else
    return exp2f(x);
#endif
}
__device__ inline void gload16(const void* g, void* lds) {
    __builtin_amdgcn_global_load_lds(
        (const __attribute__((address_space(1))) unsigned int*)g,
        (__attribute__((address_space(3))) unsigned int*)lds, 16, 0, 0);
}
#define VMCNT8() asm volatile("s_waitcnt vmcnt(8)" ::: "memory")
#define RAWBAR() __builtin_amdgcn_s_barrier()
#define SCHED0() __builtin_amdgcn_sched_barrier(0)

// ---------------- kernel 0a: W row-normalize -> fp8 e4m3, kk-INTERLEAVED ---------
// Permuted per-row byte order: pos = ks*64 + hi*16 + kk*8 + inner for original
// k-byte = ks*64 + kk*32 + hi*8 + inner.  A 16B read at row*512 + ks*64 + hi*16
// yields the (kk0,kk1) MFMA fragment pair for lane-group hi, contiguous.
__global__ __launch_bounds__(256) void rownorm8p_kernel(const float* __restrict__ in,
                                                        uint2* __restrict__ out,
                                                        int nvalid) {
    const int wid = threadIdx.x >> 6;
    const int lane = threadIdx.x & 63;
    const int r = blockIdx.x * 4 + wid;
    const int newg = ((lane >> 3) << 3) + ((lane & 3) << 1) + ((lane >> 2) & 1);
    if (r >= nvalid) {
        out[(size_t)r * 64 + newg] = make_uint2(0u, 0u);
        return;
    }
    const float* row = in + (size_t)r * D_K + lane * 8;
    float4 a = *(const float4*)row;
    float4 b = *(const float4*)(row + 4);
    float ss = a.x * a.x + a.y * a.y + a.z * a.z + a.w * a.w
             + b.x * b.x + b.y * b.y + b.z * b.z + b.w * b.w;
    ss += __shfl_xor(ss, 1);  ss += __shfl_xor(ss, 2);  ss += __shfl_xor(ss, 4);
    ss += __shfl_xor(ss, 8);  ss += __shfl_xor(ss, 16); ss += __shfl_xor(ss, 32);
    const float rn = 1.0f / sqrtf(ss);
    int u0 = __builtin_amdgcn_cvt_pk_fp8_f32(a.x * rn, a.y * rn, 0, false);
    u0     = __builtin_amdgcn_cvt_pk_fp8_f32(a.z * rn, a.w * rn, u0, true);
    int u1 = __builtin_amdgcn_cvt_pk_fp8_f32(b.x * rn, b.y * rn, 0, false);
    u1     = __builtin_amdgcn_cvt_pk_fp8_f32(b.z * rn, b.w * rn, u1, true);
    out[(size_t)r * 64 + newg] = make_uint2((unsigned)u0, (unsigned)u1);
}

// ---------------- kernel 0b: merged prep -----------------------------------------
// Blocks 0..127: normalize x rows -> fp8 kk-interleaved (same as rownorm8p).
// Blocks 128..255: self-contained target-class cosine tdot[b] = xw/sqrt(xx*ww).
__global__ __launch_bounds__(256) void prep_kernel(const float* __restrict__ x,
                                                   const float* __restrict__ w,
                                                   const int* __restrict__ tgt,
                                                   uint2* __restrict__ xnb8,
                                                   float* __restrict__ tdot) {
    const int wid = threadIdx.x >> 6;
    const int lane = threadIdx.x & 63;
    if (blockIdx.x < 128) {
        const int r = blockIdx.x * 4 + wid;
        const int newg = ((lane >> 3) << 3) + ((lane & 3) << 1) + ((lane >> 2) & 1);
        const float* row = x + (size_t)r * D_K + lane * 8;
        float4 a = *(const float4*)row;
        float4 b = *(const float4*)(row + 4);
        float ss = a.x * a.x + a.y * a.y + a.z * a.z + a.w * a.w
                 + b.x * b.x + b.y * b.y + b.z * b.z + b.w * b.w;
        ss += __shfl_xor(ss, 1);  ss += __shfl_xor(ss, 2);  ss += __shfl_xor(ss, 4);
        ss += __shfl_xor(ss, 8);  ss += __shfl_xor(ss, 16); ss += __shfl_xor(ss, 32);
        const float rn = 1.0f / sqrtf(ss);
        int u0 = __builtin_amdgcn_cvt_pk_fp8_f32(a.x * rn, a.y * rn, 0, false);
        u0     = __builtin_amdgcn_cvt_pk_fp8_f32(a.z * rn, a.w * rn, u0, true);
        int u1 = __builtin_amdgcn_cvt_pk_fp8_f32(b.x * rn, b.y * rn, 0, false);
        u1     = __builtin_amdgcn_cvt_pk_fp8_f32(b.z * rn, b.w * rn, u1, true);
        xnb8[(size_t)r * 64 + newg] = make_uint2((unsigned)u0, (unsigned)u1);
    } else {
        const int b = (blockIdx.x - 128) * 4 + wid;
        const int tg = tgt[b];
        const float* xr = x + (size_t)b * D_K + lane * 8;
        const float* wr = w + (size_t)tg * D_K + lane * 8;
        float4 xa = *(const float4*)xr;
        float4 xb = *(const float4*)(xr + 4);
        float4 wa = *(const float4*)wr;
        float4 wb = *(const float4*)(wr + 4);
        float xw = xa.x * wa.x + xa.y * wa.y + xa.z * wa.z + xa.w * wa.w
                 + xb.x * wb.x + xb.y * wb.y + xb.z * wb.z + xb.w * wb.w;
        float ww = wa.x * wa.x + wa.y * wa.y + wa.z * wa.z + wa.w * wa.w
                 + wb.x * wb.x + wb.y * wb.y + wb.z * wb.z + wb.w * wb.w;
        float xx = xa.x * xa.x + xa.y * xa.y + xa.z * xa.z + xa.w * xa.w
                 + xb.x * xb.x + xb.y * xb.y + xb.z * xb.z + xb.w * xb.w;
#pragma unroll
        for (int m = 1; m < 64; m <<= 1) {
            xw += __shfl_xor(xw, m);
            ww += __shfl_xor(ww, m);
            xx += __shfl_xor(xx, m);
        }
        if (lane == 0) tdot[b] = xw / sqrtf(xx * ww);
    }
}

// ---------------- kernel 1: fp8 strip GEMM, half-chunk ring-4, counted vmcnt -----
// (byte-identical to the r15/r20 proven kernel)
__global__ __launch_bounds__(256, 2) void gemm_ring_kernel(
        const unsigned char* __restrict__ xnb8p,  // [512][512] fp8 norm, interleaved
        const unsigned char* __restrict__ wn8p,   // [C_PAD][512] fp8 norm, interleaved
        float* __restrict__ partials) {           // [NSTRIP][512]
    const int t    = threadIdx.x;
    const int lane = t & 63;
    const int wid  = t >> 6;
    const int cl   = lane & 15;
    const int hi   = lane >> 4;
    const int swz  = (cl >> 1) & 3;

    const int j   = blockIdx.x;
    const int s   = (j & 7) * 32 + ((j >> 3) >> 1);   // col-strip 0..255
    const int rb  = (j >> 3) & 1;                     // rowblock
    const int ch0 = (s * NCHUNK) >> 8;
    const int ch1 = ((s + 1) * NCHUNK) >> 8;
    const int nch = ch1 - ch0;
    const int cbase = ch0 * BN;
    const int H   = nch * 2;                          // half-chunks

    __shared__ char smem[4 * 16384];                  // 64 KB ring

    const int srow = t >> 2;
    const int sgl  = (lane & 3) ^ ((lane >> 3) & 3);

#define STAGEH(hsrc, bufi)                                                      \
    {                                                                           \
        const int _ci = (hsrc) >> 1, _kh = (hsrc) & 1;                          \
        const unsigned char* _b = wn8p +                                        \
            (size_t)(cbase + _ci * 64 + srow) * 512 + _kh * 256 + (sgl << 4);   \
        char* _d = smem + (bufi) * 16384 + wid * 1024;                          \
        _Pragma("unroll")                                                       \
        for (int _j = 0; _j < 4; ++_j)                                          \
            gload16(_b + _j * 64, _d + _j * 4096);                              \
    }

    // ---- A: 64 rows/wave, full K, fp8 pinned in regs (direct global loads) ----
    i64 a8[4][16];
#pragma unroll
    for (int m = 0; m < 4; ++m) {
        const unsigned char* ap =
            xnb8p + (size_t)(rb * 256 + wid * 64 + m * 16 + cl) * 512 + hi * 16;
#pragma unroll
        for (int k = 0; k < 8; ++k) {
            i64x2 q = *(const i64x2*)(ap + k * 64);
            a8[m][k * 2]     = q[0];
            a8[m][k * 2 + 1] = q[1];
        }
    }
#pragma unroll
    for (int m = 0; m < 4; ++m)
#pragma unroll
        for (int i = 0; i < 16; ++i)
            asm volatile("" : "+v"(a8[m][i]));   // forces vmcnt wait + pins A

    // ---- prologue: stage half-chunks 0,1 (8 loads outstanding) ----
    STAGEH(0, 0)
    STAGEH(1, 1)

    float sums[16];
#pragma unroll
    for (int i = 0; i < 16; ++i) sums[i] = 0.f;

#define COMPUTE_HALF(bufbyte, KH)                                               \
    {                                                                           \
        const char* sB = smem + (bufbyte);                                      \
        _Pragma("unroll")                                                       \
        for (int k = 0; k < 4; ++k) {                                           \
            i64x2 bfr[4];                                                       \
            _Pragma("unroll")                                                   \
            for (int n = 0; n < 4; ++n)                                         \
                bfr[n] = *(const i64x2*)(sB + k * 4096 + (n * 16 + cl) * 64 +   \
                                         ((hi ^ swz) << 4));                    \
            _Pragma("unroll")                                                   \
            for (int m = 0; m < 4; ++m)                                         \
                _Pragma("unroll")                                               \
                for (int n = 0; n < 4; ++n)                                     \
                    acc[m][n] = __builtin_amdgcn_mfma_f32_16x16x32_fp8_fp8(     \
                        a8[m][((KH) * 4 + k) * 2], bfr[n][0], acc[m][n],        \
                        0, 0, 0);                                               \
            _Pragma("unroll")                                                   \
            for (int m = 0; m < 4; ++m)                                         \
                _Pragma("unroll")                                               \
                for (int n = 0; n < 4; ++n)                                     \
                    acc[m][n] = __builtin_amdgcn_mfma_f32_16x16x32_fp8_fp8(     \
                        a8[m][((KH) * 4 + k) * 2 + 1], bfr[n][1], acc[m][n],    \
                        0, 0, 0);                                               \
        }                                                                       \
    }

    for (int ci = 0; ci < nch; ++ci) {
        const int sbase = (ci & 1) << 1;
        const int dbase = sbase ^ 2;
        const int h0 = 2 * ci, h1 = h0 + 1;

        f32x4 acc[4][4];
#pragma unroll
        for (int m = 0; m < 4; ++m)
#pragma unroll
            for (int n = 0; n < 4; ++n) acc[m][n] = (f32x4){0.f, 0.f, 0.f, 0.f};

        // ---- half 0 ----
        {
            const int hs = (h0 + 2 < H) ? h0 + 2 : H - 1;
            STAGEH(hs, dbase)
        }
        SCHED0();
        VMCNT8();
        RAWBAR();
        COMPUTE_HALF(sbase * 16384, 0)

        // ---- half 1 ----
        {
            const int hs = (h1 + 2 < H) ? h1 + 2 : H - 1;
            STAGEH(hs, dbase + 1)
        }
        SCHED0();
        VMCNT8();
        RAWBAR();
        COMPUTE_HALF((sbase + 1) * 16384, 1)

        // ---- chunk epilogue: fixed-M0 accumulation (pad rows -> 2^-92.4 ~ 0) ----
#pragma unroll
        for (int m = 0; m < 4; ++m)
#pragma unroll
            for (int jj = 0; jj < 4; ++jj)
#pragma unroll
                for (int n = 0; n < 4; ++n)
                    sums[m * 4 + jj] += fexp2(fmaf(acc[m][n][jj], LOG2E_S, -M0));
    }
#undef STAGEH
#undef COMPUTE_HALF

    // ---- strip epilogue: reduce each tracked row across its 16 col-lanes ----
#pragma unroll
    for (int m = 0; m < 4; ++m)
#pragma unroll
        for (int jj = 0; jj < 4; ++jj) {
            float v = sums[m * 4 + jj];
            v += __shfl_xor(v, 1);
            v += __shfl_xor(v, 2);
            v += __shfl_xor(v, 4);
            v += __shfl_xor(v, 8);
            if (cl == 0) {
                const int r = rb * 256 + wid * 64 + m * 16 + hi * 4 + jj;
                partials[s * B_ROWS + r] = v;
            }
        }
}

// ---------------- kernel 3: per-row loss (margin fixup) + mean ----------------
__global__ __launch_bounds__(512) void final_kernel(const float* __restrict__ partials,
                                                    const float* __restrict__ tdot,
                                                    float* __restrict__ out) {
    const int b = threadIdx.x;   // 512 threads = 8 waves
    float s2 = 0.f;
    for (int s = 0; s < NSTRIP; ++s) s2 += partials[s * B_ROWS + b];
    const float cst = tdot[b];
    float c2 = 1.0f - cst * cst;
    c2 = fminf(fmaxf(c2, 0.0f), 1.0f);
    const float sine = sqrtf(c2);
    float phi = cst * COS_M - sine * SIN_M;
    phi = (cst > TH_C) ? phi : (cst - MM_C);
    const float Lt = cst * LOG2E_S;
    const float Lp = phi * LOG2E_S;
    // swap plain-target term for margin term in the denominator
    s2 = s2 - fexp2(Lt - M0) + fexp2(Lp - M0);
    float loss = LN2F * (M0 + log2f(s2) - Lp);
    loss += __shfl_xor(loss, 1);  loss += __shfl_xor(loss, 2);
    loss += __shfl_xor(loss, 4);  loss += __shfl_xor(loss, 8);
    loss += __shfl_xor(loss, 16); loss += __shfl_xor(loss, 32);
    __shared__ float sW[8];
    if ((b & 63) == 0) sW[b >> 6] = loss;
    __syncthreads();
    if (b == 0) {
        float tot = 0.f;
#pragma unroll
        for (int wv = 0; wv < 8; ++wv) tot += sW[wv];
        out[0] = tot * (1.0f / (float)B_ROWS);
    }
}

extern "C" void kernel_launch(void* const* d_in, const int* in_sizes, int n_in,
                              void* d_out, int out_size, void* d_ws, size_t ws_size,
                              hipStream_t stream) {
    const float* x = (const float*)d_in[0];
    const float* w = (const float*)d_in[1];
    const int* tgt = (const int*)d_in[2];
    float* out = (float*)d_out;

    char* ws = (char*)d_ws;
    size_t off = 0;
    unsigned char* xnb8 = (unsigned char*)(ws + off);
    off += (size_t)B_ROWS * D_K;                       // 256 KB
    off = (off + 255) & ~(size_t)255;
    unsigned char* wn8 = (unsigned char*)(ws + off);
    off += (size_t)C_PAD * D_K;                        // 51.2 MB
    off = (off + 255) & ~(size_t)255;
    float* partials = (float*)(ws + off);
    off += (size_t)NSTRIP * B_ROWS * 4;                // 512 KB
    off = (off + 255) & ~(size_t)255;
    float* tdot = (float*)(ws + off);
    off += B_ROWS * 4;

    prep_kernel<<<256, 256, 0, stream>>>(x, w, tgt, (uint2*)xnb8, tdot);
    rownorm8p_kernel<<<C_PAD / 4, 256, 0, stream>>>(w, (uint2*)wn8, C_CLS);
    gemm_ring_kernel<<<NSTRIP * 2, 256, 0, stream>>>(xnb8, wn8, partials);
    final_kernel<<<1, 512, 0, stream>>>(partials, tdot, out);
}